// Round 4
// baseline (721.342 us; speedup 1.0000x reference)
//
#include <hip/hip_runtime.h>
#include <hip/hip_bf16.h>

typedef unsigned short u16;
typedef unsigned int u32;
typedef __attribute__((ext_vector_type(8))) short short8;   // bf16x8 MFMA frag (4 VGPR)
typedef __attribute__((ext_vector_type(4))) float float4v;  // fp32x4 acc
typedef __attribute__((ext_vector_type(4))) unsigned int uint4v; // 16B vector
typedef __attribute__((ext_vector_type(2))) unsigned int uint2v; // 8B vector

__device__ __forceinline__ u16 f2bf(float f) {
    union { float f; unsigned int u; } v; v.f = f;
    unsigned int r = v.u + 0x7fffu + ((v.u >> 16) & 1u);  // RNE
    return (u16)(r >> 16);
}

// packed fp32x2 -> bf16x2 (no builtin on gfx950; T12 recipe)
__device__ __forceinline__ u32 cvtpk(float lo, float hi) {
    u32 r;
    asm("v_cvt_pk_bf16_f32 %0, %1, %2" : "=v"(r) : "v"(lo), "v"(hi));
    return r;
}
// bf16 pair unpack: element 0 is low u16, element 1 is high u16
__device__ __forceinline__ float bflo(u32 u) {
    union { u32 u; float f; } v; v.u = u << 16; return v.f;
}
__device__ __forceinline__ float bfhi(u32 u) {
    union { u32 u; float f; } v; v.u = u & 0xffff0000u; return v.f;
}

// async 16B global -> LDS (lane i lands at ldsbase + i*16)
__device__ __forceinline__ void gld_lds16(const u16* g, u16* l) {
    __builtin_amdgcn_global_load_lds(
        (const __attribute__((address_space(1))) u32*)g,
        (__attribute__((address_space(3))) u32*)l, 16, 0, 0);
}

// ---------------------------------------------------------------------------
// x: fp32 [8192*1024] -> bf16. 8 elements/thread.
// ---------------------------------------------------------------------------
__global__ __launch_bounds__(256) void convert_x(
    const float* __restrict__ x, u16* __restrict__ xb) {
    int i = (blockIdx.x * 256 + threadIdx.x) * 8;
    float4v a = *(const float4v*)&x[i];
    float4v b = *(const float4v*)&x[i + 4];
    u16 tmp[8] __attribute__((aligned(16)));
#pragma unroll
    for (int j = 0; j < 4; ++j) { tmp[j] = f2bf(a[j]); tmp[4 + j] = f2bf(b[j]); }
    *(uint4v*)&xb[i] = *(uint4v*)tmp;
}

// ---------------------------------------------------------------------------
// Weight transpose+convert: W fp32 [1024][1024] (K x N) -> Wt bf16 (N x K).
// ---------------------------------------------------------------------------
__global__ __launch_bounds__(256) void transpose_w(
    const float* __restrict__ w0, const float* __restrict__ w1,
    const float* __restrict__ w2, const float* __restrict__ w3,
    u16* __restrict__ o0, u16* __restrict__ o1,
    u16* __restrict__ o2, u16* __restrict__ o3) {
    __shared__ u16 t[32][33];
    int z = blockIdx.z;
    const float* w = (z == 0) ? w0 : (z == 1) ? w1 : (z == 2) ? w2 : w3;
    u16* o         = (z == 0) ? o0 : (z == 1) ? o1 : (z == 2) ? o2 : o3;
    int bx = blockIdx.x * 32;   // input col (n)
    int by = blockIdx.y * 32;   // input row (k)
    int x = threadIdx.x, y = threadIdx.y;   // block (32,8)
#pragma unroll
    for (int i = 0; i < 4; ++i)
        t[y + i * 8][x] = f2bf(w[(size_t)(by + y + i * 8) * 1024 + bx + x]);
    __syncthreads();
#pragma unroll
    for (int i = 0; i < 4; ++i)
        o[(size_t)(bx + y + i * 8) * 1024 + by + x] = t[x][y + i * 8];
}

// ---------------------------------------------------------------------------
// GEMM: C[M][N] = A[M][K] @ Bt[N][K]^T, bf16 in, fp32 accum.
// mode 0: bf16 out, scaled by oscale (folds softmax scale into Q proj)
// mode 1: bf16 out, transposed [b*1024+f][2048] (V)
// mode 2: fp32 out (final projection)
// ---------------------------------------------------------------------------
__global__ __launch_bounds__(256) void gemm_bt(
    const u16* __restrict__ A, const u16* __restrict__ Bt,
    void* __restrict__ Cout, int M, int N, int K, int mode, float oscale) {
    __shared__ __attribute__((aligned(16))) u16 As[128 * 32];
    __shared__ __attribute__((aligned(16))) u16 Bs[128 * 32];
    const int tid = threadIdx.x;
    const int m0 = blockIdx.y * 128;
    const int n0 = blockIdx.x * 128;
    const int wid = tid >> 6;
    const int lane = tid & 63;
    const int ln = lane & 15, kq = lane >> 4;
    const int wm = (wid >> 1) * 64, wn = (wid & 1) * 64;

    float4v acc[4][4] = {};
    for (int k0 = 0; k0 < K; k0 += 32) {
#pragma unroll
        for (int i = 0; i < 2; ++i) {
            int chunk = tid + i * 256;          // 16B chunk id, 0..511
            int row = chunk >> 2, cg = chunk & 3;
            u16* lA = &As[(size_t)(i * 256 + wid * 64) * 8];
            u16* lB = &Bs[(size_t)(i * 256 + wid * 64) * 8];
            gld_lds16(&A[(size_t)(m0 + row) * K + k0 + cg * 8], lA);
            gld_lds16(&Bt[(size_t)(n0 + row) * K + k0 + cg * 8], lB);
        }
        __syncthreads();
        short8 af[4], bfr[4];
#pragma unroll
        for (int mt = 0; mt < 4; ++mt)
            af[mt] = *(const short8*)&As[(wm + mt * 16 + ln) * 32 + kq * 8];
#pragma unroll
        for (int nt = 0; nt < 4; ++nt)
            bfr[nt] = *(const short8*)&Bs[(wn + nt * 16 + ln) * 32 + kq * 8];
#pragma unroll
        for (int mt = 0; mt < 4; ++mt)
#pragma unroll
            for (int nt = 0; nt < 4; ++nt)
                acc[mt][nt] = __builtin_amdgcn_mfma_f32_16x16x32_bf16(
                    af[mt], bfr[nt], acc[mt][nt], 0, 0, 0);
        __syncthreads();
    }
    if (mode == 0) {
        u16* C = (u16*)Cout;
#pragma unroll
        for (int mt = 0; mt < 4; ++mt)
#pragma unroll
            for (int nt = 0; nt < 4; ++nt)
#pragma unroll
                for (int r = 0; r < 4; ++r) {
                    int row = m0 + wm + mt * 16 + kq * 4 + r;
                    int col = n0 + wn + nt * 16 + ln;
                    C[(size_t)row * N + col] = f2bf(acc[mt][nt][r] * oscale);
                }
    } else if (mode == 1) {
        u16* C = (u16*)Cout;
#pragma unroll
        for (int mt = 0; mt < 4; ++mt)
#pragma unroll
            for (int nt = 0; nt < 4; ++nt)
#pragma unroll
                for (int r = 0; r < 4; ++r) {
                    int t = m0 + wm + mt * 16 + kq * 4 + r;
                    int col = n0 + wn + nt * 16 + ln;
                    int b = t >> 11, n = t & 2047;
                    C[((size_t)(b * 1024 + col)) * 2048 + n] = f2bf(acc[mt][nt][r]);
                }
    } else {
        float* C = (float*)Cout;
#pragma unroll
        for (int mt = 0; mt < 4; ++mt)
#pragma unroll
            for (int nt = 0; nt < 4; ++nt)
#pragma unroll
                for (int r = 0; r < 4; ++r) {
                    int row = m0 + wm + mt * 16 + kq * 4 + r;
                    int col = n0 + wn + nt * 16 + ln;
                    C[(size_t)row * N + col] = acc[mt][nt][r];
                }
    }
}

// ---------------------------------------------------------------------------
// Fused attention, head-axis softmax.  R9: 2 blocks/CU via small footprint.
//  * q-tile 16, grid (128,4)=512 blocks, 1024 thr (1 head/wave).
//  * E bf16 in LDS (2 ping-pong buffers) -> LDS 39168 B -> 2 blocks/CU.
//  * __launch_bounds__(1024, 2): HIP 2nd arg = min BLOCKS/CU (R6/R8 counter
//    evidence: (1024,8)->VGPR 32, (1024,4)->64).  Cap 64 VGPR; q16 live set
//    aq(8)+bk(16)+bv(16)+temps fits (cacc in AGPRs) -- no spills.
//  * Two blocks per CU are barrier-independent: one block's MFMA fills the
//    other's Dsum/barrier windows -- the overlap R8 failed to get in-block.
//  * R7 2-barrier structure otherwise unchanged; all LDS phases at bank floor
//    (stride 36 u16 / 36 f32 verified per-phase).
// LDS = 2*18432 (E) + 2304 (Di) = 39168 B.
// qb/cb alias -- block reads its own 16 Q rows before writing same rows.
// ---------------------------------------------------------------------------
__global__ __launch_bounds__(1024, 2) void attn_kernel(
    const u16* qb, const u16* __restrict__ kb,
    const u16* __restrict__ vt, u16* cb) {
    // E rows = h*16+q (256 rows), cols k 0..31 bf16, stride 36 u16 (72 B)
    __shared__ __attribute__((aligned(16))) u16   Ebuf[2][256 * 36]; // 36864 B
    __shared__ __attribute__((aligned(16))) float Di[16 * 36];       //  2304 B

    const int b = blockIdx.y;
    const int q0 = blockIdx.x * 16;
    const int tid = threadIdx.x;
    const int wid = tid >> 6, lane = tid & 63;   // wid 0..15 = head
    const int ln = lane & 15, kq = lane >> 4;
    const int h = wid;

    // Preload Q fragments (already scaled by 0.125*log2e in the Q GEMM)
    short8 aq[2];   // [kc]
#pragma unroll
    for (int kc = 0; kc < 2; ++kc)
        aq[kc] = *(const short8*)&qb[
            (size_t)(b * 2048 + q0 + ln) * 1024 + h * 64 + kc * 32 + kq * 8];

    float4v cacc[4] = {};   // [nt] ctx accumulators (16q x 64d), in AGPRs

#pragma unroll 1
    for (int kt = 0; kt < 2048; kt += 32) {
        const int cur = (kt >> 5) & 1;
        u16* E = Ebuf[cur];

        // ---- S^T = K @ Q^T for this head (C: col=q=ln, row=k=kq*4+r)
        short8 bk[2][2];   // [kc][nt]
#pragma unroll
        for (int kc = 0; kc < 2; ++kc)
#pragma unroll
            for (int nt = 0; nt < 2; ++nt)
                bk[kc][nt] = *(const short8*)&kb[
                    (size_t)(b * 2048 + kt + nt * 16 + ln) * 1024 +
                    h * 64 + kc * 32 + kq * 8];

        float4v sacc[2] = {};   // [nt]
#pragma unroll
        for (int kc = 0; kc < 2; ++kc)
#pragma unroll
            for (int nt = 0; nt < 2; ++nt)
                sacc[nt] = __builtin_amdgcn_mfma_f32_16x16x32_bf16(
                    bk[kc][nt], aq[kc], sacc[nt], 0, 0, 0);

        // ---- E = exp2(S) -> bf16, one b64 store per nt (4 consecutive k)
#pragma unroll
        for (int nt = 0; nt < 2; ++nt) {
            float e0 = exp2f(fminf(sacc[nt][0], 115.0f));
            float e1 = exp2f(fminf(sacc[nt][1], 115.0f));
            float e2 = exp2f(fminf(sacc[nt][2], 115.0f));
            float e3 = exp2f(fminf(sacc[nt][3], 115.0f));
            uint2v w; w[0] = cvtpk(e0, e1); w[1] = cvtpk(e2, e3);
            *(uint2v*)&E[(h * 16 + ln) * 36 + nt * 16 + kq * 4] = w;
        }

        // ---- hoisted V gather (consumed after BAR-B; hides global latency)
        short8 bv[4];
#pragma unroll
        for (int nt = 0; nt < 4; ++nt)
            bv[nt] = *(const short8*)&vt[
                (size_t)(b * 1024 + h * 64 + nt * 16 + ln) * 2048 + kt + kq * 8];

        __syncthreads();   // BAR-A: E[cur] complete

        // ---- Dinv = 1 / sum_h E  (2 waves, b64 reads; bank floor)
        if (tid < 128) {
            const int q = tid >> 3, k4 = tid & 7;   // k = k4*4 .. +3
            float d0 = 0.f, d1 = 0.f, d2 = 0.f, d3 = 0.f;
#pragma unroll
            for (int hh = 0; hh < 16; ++hh) {
                uint2v e = *(const uint2v*)&E[(hh * 16 + q) * 36 + k4 * 4];
                d0 += bflo(e[0]); d1 += bfhi(e[0]);
                d2 += bflo(e[1]); d3 += bfhi(e[1]);
            }
            float4v dv;
            dv[0] = __builtin_amdgcn_rcpf(d0);
            dv[1] = __builtin_amdgcn_rcpf(d1);
            dv[2] = __builtin_amdgcn_rcpf(d2);
            dv[3] = __builtin_amdgcn_rcpf(d3);
            *(float4v*)&Di[q * 36 + k4 * 4] = dv;
        }
        __syncthreads();   // BAR-B: Di complete

        // ---- A-frag = (E * Dinv) packed bf16 via cvt_pk; ctx += A @ V
        const u16* ep = &E[(h * 16 + ln) * 36 + kq * 8];
        uint2v ea = *(const uint2v*)&ep[0];   // k = 8kq+0..3
        uint2v eb = *(const uint2v*)&ep[4];   // k = 8kq+4..7
        const float* dp = &Di[ln * 36 + kq * 8];
        float4v g0 = *(const float4v*)&dp[0];
        float4v g1 = *(const float4v*)&dp[4];
        u32 pk[4] __attribute__((aligned(16)));
        pk[0] = cvtpk(bflo(ea[0]) * g0[0], bfhi(ea[0]) * g0[1]);
        pk[1] = cvtpk(bflo(ea[1]) * g0[2], bfhi(ea[1]) * g0[3]);
        pk[2] = cvtpk(bflo(eb[0]) * g1[0], bfhi(eb[0]) * g1[1]);
        pk[3] = cvtpk(bflo(eb[1]) * g1[2], bfhi(eb[1]) * g1[3]);
        short8 ap = *(short8*)pk;
#pragma unroll
        for (int nt = 0; nt < 4; ++nt)
            cacc[nt] = __builtin_amdgcn_mfma_f32_16x16x32_bf16(
                ap, bv[nt], cacc[nt], 0, 0, 0);
    }

    // Epilogue: ctx[b*2048+q][h*64+d], bf16  (cb aliases qb -- same rows only)
#pragma unroll
    for (int nt = 0; nt < 4; ++nt)
#pragma unroll
        for (int r = 0; r < 4; ++r) {
            int row = b * 2048 + q0 + kq * 4 + r;
            int col = h * 64 + nt * 16 + ln;
            cb[(size_t)row * 1024 + col] = f2bf(cacc[nt][r]);
        }
}

// ---------------------------------------------------------------------------
extern "C" void kernel_launch(void* const* d_in, const int* in_sizes, int n_in,
                              void* d_out, int out_size, void* d_ws, size_t ws_size,
                              hipStream_t stream) {
    const float* x   = (const float*)d_in[0];   // [8192][1024] fp32
    const float* w_q = (const float*)d_in[1];   // [1024][1024] fp32 (K x N)
    const float* w_k = (const float*)d_in[2];
    const float* w_v = (const float*)d_in[3];
    const float* w_o = (const float*)d_in[4];

    char* ws = (char*)d_ws;
    const size_t SZ_W   = (size_t)1024 * 1024 * 2;   // 2 MiB
    const size_t SZ_TOK = (size_t)8192 * 1024 * 2;   // 16 MiB
    // ws layout (40 MiB): x_bf | wtq wtk wtv wto | q_buf(=ctx)
    u16* x_bf  = (u16*)(ws);
    u16* wtq   = (u16*)(ws + SZ_TOK);
    u16* wtk   = (u16*)(ws + SZ_TOK + SZ_W);
    u16* wtv   = (u16*)(ws + SZ_TOK + 2 * SZ_W);
    u16* wto   = (u16*)(ws + SZ_TOK + 3 * SZ_W);
    u16* q_buf = (u16*)(ws + SZ_TOK + 4 * SZ_W);     // also ctx (aliased)
    // k_buf / vt_buf live in d_out (32 MiB fp32) -- dead before final GEMM writes it
    u16* k_buf  = (u16*)d_out;
    u16* vt_buf = (u16*)d_out + (size_t)8192 * 1024;

    // 0. convert x to bf16
    convert_x<<<4096, 256, 0, stream>>>(x, x_bf);

    // 1. transpose+convert weights to Bt (N x K) bf16 layout
    transpose_w<<<dim3(32, 32, 4), dim3(32, 8), 0, stream>>>(
        w_q, w_k, w_v, w_o, wtq, wtk, wtv, wto);

    // 2. QKV projections (Q pre-scaled by 0.125*log2e for exp2-domain scores;
    //    V written directly in transposed [b*1024+f][2048] layout)
    gemm_bt<<<dim3(8, 64), 256, 0, stream>>>(x_bf, wtq, q_buf, 8192, 1024, 1024, 0, 0.18033688f);
    gemm_bt<<<dim3(8, 64), 256, 0, stream>>>(x_bf, wtk, k_buf, 8192, 1024, 1024, 0, 1.0f);
    gemm_bt<<<dim3(8, 64), 256, 0, stream>>>(x_bf, wtv, vt_buf, 8192, 1024, 1024, 1, 1.0f);

    // 3. fused attention with head-axis softmax (ctx written into q_buf)
    attn_kernel<<<dim3(128, 4), 1024, 0, stream>>>(q_buf, k_buf, vt_buf, q_buf);

    // 4. output projection -> fp32 d_out (overwrites k_buf/vt_buf scratch)
    gemm_bt<<<dim3(8, 64), 256, 0, stream>>>(q_buf, wto, d_out, 8192, 1024, 1024, 2, 1.0f);
}

// Round 5
// 547.033 us; speedup vs baseline: 1.3186x; 1.3186x over previous
//
#include <hip/hip_runtime.h>
#include <hip/hip_bf16.h>

typedef unsigned short u16;
typedef unsigned int u32;
typedef __attribute__((ext_vector_type(8))) short short8;   // bf16x8 MFMA frag (4 VGPR)
typedef __attribute__((ext_vector_type(4))) float float4v;  // fp32x4 acc
typedef __attribute__((ext_vector_type(4))) unsigned int uint4v; // 16B vector

__device__ __forceinline__ u16 f2bf(float f) {
    union { float f; unsigned int u; } v; v.f = f;
    unsigned int r = v.u + 0x7fffu + ((v.u >> 16) & 1u);  // RNE
    return (u16)(r >> 16);
}

// packed fp32x2 -> bf16x2 (no builtin on gfx950; T12 recipe)
__device__ __forceinline__ u32 cvtpk(float lo, float hi) {
    u32 r;
    asm("v_cvt_pk_bf16_f32 %0, %1, %2" : "=v"(r) : "v"(lo), "v"(hi));
    return r;
}

// async 16B global -> LDS (lane i lands at ldsbase + i*16)
__device__ __forceinline__ void gld_lds16(const u16* g, u16* l) {
    __builtin_amdgcn_global_load_lds(
        (const __attribute__((address_space(1))) u32*)g,
        (__attribute__((address_space(3))) u32*)l, 16, 0, 0);
}

// ---------------------------------------------------------------------------
// x: fp32 [8192*1024] -> bf16. 8 elements/thread.
// ---------------------------------------------------------------------------
__global__ __launch_bounds__(256) void convert_x(
    const float* __restrict__ x, u16* __restrict__ xb) {
    int i = (blockIdx.x * 256 + threadIdx.x) * 8;
    float4v a = *(const float4v*)&x[i];
    float4v b = *(const float4v*)&x[i + 4];
    u16 tmp[8] __attribute__((aligned(16)));
#pragma unroll
    for (int j = 0; j < 4; ++j) { tmp[j] = f2bf(a[j]); tmp[4 + j] = f2bf(b[j]); }
    *(uint4v*)&xb[i] = *(uint4v*)tmp;
}

// ---------------------------------------------------------------------------
// zero a buffer, 16B/thread
// ---------------------------------------------------------------------------
__global__ __launch_bounds__(256) void zero_buf(uint4v* __restrict__ p) {
    uint4v z = {0u, 0u, 0u, 0u};
    p[(size_t)blockIdx.x * 256 + threadIdx.x] = z;
}

// ---------------------------------------------------------------------------
// Weight transpose+convert: W fp32 [1024][1024] (K x N) -> Wt bf16 (N x K).
// ---------------------------------------------------------------------------
__global__ __launch_bounds__(256) void transpose_w(
    const float* __restrict__ w0, const float* __restrict__ w1,
    const float* __restrict__ w2, const float* __restrict__ w3,
    u16* __restrict__ o0, u16* __restrict__ o1,
    u16* __restrict__ o2, u16* __restrict__ o3) {
    __shared__ u16 t[32][33];
    int z = blockIdx.z;
    const float* w = (z == 0) ? w0 : (z == 1) ? w1 : (z == 2) ? w2 : w3;
    u16* o         = (z == 0) ? o0 : (z == 1) ? o1 : (z == 2) ? o2 : o3;
    int bx = blockIdx.x * 32;   // input col (n)
    int by = blockIdx.y * 32;   // input row (k)
    int x = threadIdx.x, y = threadIdx.y;   // block (32,8)
#pragma unroll
    for (int i = 0; i < 4; ++i)
        t[y + i * 8][x] = f2bf(w[(size_t)(by + y + i * 8) * 1024 + bx + x]);
    __syncthreads();
#pragma unroll
    for (int i = 0; i < 4; ++i)
        o[(size_t)(bx + y + i * 8) * 1024 + by + x] = t[x][y + i * 8];
}

// ---------------------------------------------------------------------------
// GEMM: C[M][N] = A[M][K] @ Bt[N][K]^T, bf16 in, fp32 accum.
// mode 0: bf16 out, scaled by oscale (folds softmax scale into Q proj)
// mode 1: bf16 out, transposed [b*1024+f][2048] (V)
// mode 2: fp32 out (final projection)
// ---------------------------------------------------------------------------
__global__ __launch_bounds__(256) void gemm_bt(
    const u16* __restrict__ A, const u16* __restrict__ Bt,
    void* __restrict__ Cout, int M, int N, int K, int mode, float oscale) {
    __shared__ __attribute__((aligned(16))) u16 As[128 * 32];
    __shared__ __attribute__((aligned(16))) u16 Bs[128 * 32];
    const int tid = threadIdx.x;
    const int m0 = blockIdx.y * 128;
    const int n0 = blockIdx.x * 128;
    const int wid = tid >> 6;
    const int lane = tid & 63;
    const int ln = lane & 15, kq = lane >> 4;
    const int wm = (wid >> 1) * 64, wn = (wid & 1) * 64;

    float4v acc[4][4] = {};
    for (int k0 = 0; k0 < K; k0 += 32) {
#pragma unroll
        for (int i = 0; i < 2; ++i) {
            int chunk = tid + i * 256;          // 16B chunk id, 0..511
            int row = chunk >> 2, cg = chunk & 3;
            u16* lA = &As[(size_t)(i * 256 + wid * 64) * 8];
            u16* lB = &Bs[(size_t)(i * 256 + wid * 64) * 8];
            gld_lds16(&A[(size_t)(m0 + row) * K + k0 + cg * 8], lA);
            gld_lds16(&Bt[(size_t)(n0 + row) * K + k0 + cg * 8], lB);
        }
        __syncthreads();
        short8 af[4], bfr[4];
#pragma unroll
        for (int mt = 0; mt < 4; ++mt)
            af[mt] = *(const short8*)&As[(wm + mt * 16 + ln) * 32 + kq * 8];
#pragma unroll
        for (int nt = 0; nt < 4; ++nt)
            bfr[nt] = *(const short8*)&Bs[(wn + nt * 16 + ln) * 32 + kq * 8];
#pragma unroll
        for (int mt = 0; mt < 4; ++mt)
#pragma unroll
            for (int nt = 0; nt < 4; ++nt)
                acc[mt][nt] = __builtin_amdgcn_mfma_f32_16x16x32_bf16(
                    af[mt], bfr[nt], acc[mt][nt], 0, 0, 0);
        __syncthreads();
    }
    if (mode == 0) {
        u16* C = (u16*)Cout;
#pragma unroll
        for (int mt = 0; mt < 4; ++mt)
#pragma unroll
            for (int nt = 0; nt < 4; ++nt)
#pragma unroll
                for (int r = 0; r < 4; ++r) {
                    int row = m0 + wm + mt * 16 + kq * 4 + r;
                    int col = n0 + wn + nt * 16 + ln;
                    C[(size_t)row * N + col] = f2bf(acc[mt][nt][r] * oscale);
                }
    } else if (mode == 1) {
        u16* C = (u16*)Cout;
#pragma unroll
        for (int mt = 0; mt < 4; ++mt)
#pragma unroll
            for (int nt = 0; nt < 4; ++nt)
#pragma unroll
                for (int r = 0; r < 4; ++r) {
                    int t = m0 + wm + mt * 16 + kq * 4 + r;
                    int col = n0 + wn + nt * 16 + ln;
                    int b = t >> 11, n = t & 2047;
                    C[((size_t)(b * 1024 + col)) * 2048 + n] = f2bf(acc[mt][nt][r]);
                }
    } else {
        float* C = (float*)Cout;
#pragma unroll
        for (int mt = 0; mt < 4; ++mt)
#pragma unroll
            for (int nt = 0; nt < 4; ++nt)
#pragma unroll
                for (int r = 0; r < 4; ++r) {
                    int row = m0 + wm + mt * 16 + kq * 4 + r;
                    int col = n0 + wn + nt * 16 + ln;
                    C[(size_t)row * N + col] = acc[mt][nt][r];
                }
    }
}

// ---------------------------------------------------------------------------
// Fused attention, head-axis softmax.  R10 = R7 structure + L2 locality:
//  * Counter evidence R7/R9: time tracks redundant K/V gather bytes at a
//    ~7.5 TB/s L2/L3-path ceiling (per-batch K+V = 8 MB > 4 MB L2/XCD).
//  * k-half split: each block owns keys [kh*1024, kh*1024+1024).  Head-axis
//    softmax normalizes per (q,k) over heads -- no coupling across k -- so
//    ctx halves combine by PURE ADDITION (atomic pk_add_bf16, zeroed ctx).
//  * XCD pinning: blockIdx.x = qt*8 + (b*2+kh); round-robin dispatch puts
//    all 64 q-blocks sharing one (batch, k-half) on ONE XCD whose 4 MB L2
//    exactly holds that K/V half -> the 64x reuse becomes L2-resident.
//  * Everything else identical to the proven R7 kernel (fp32 E stride 36,
//    2 barriers/tile, plain launch_bounds(1024): VGPR 64 + 32 AGPR, 0 spill).
// LDS = 2*73728 (E) + 4608 (Di) = 152064 B.
// ctx is a SEPARATE buffer now (atomics) -- no qb aliasing.
// ---------------------------------------------------------------------------
__global__ __launch_bounds__(1024) void attn_kernel(
    const u16* __restrict__ qb, const u16* __restrict__ kb,
    const u16* __restrict__ vt, u16* __restrict__ ctx) {
    // rows = h*32+q (512 rows), cols k 0..31, stride 36 fp32
    __shared__ __attribute__((aligned(16))) float Ef[2][512 * 36]; // 147456 B
    __shared__ __attribute__((aligned(16))) float Di[32 * 36];     //   4608 B

    const int bx = blockIdx.x;          // 0..511
    const int qt = bx >> 3;             // 0..63
    const int slot = bx & 7;            // XCD slot = b*2 + kh
    const int b = slot >> 1, kh = slot & 1;
    const int q0 = qt * 32;
    const int tid = threadIdx.x;
    const int wid = tid >> 6, lane = tid & 63;   // wid 0..15 = head
    const int ln = lane & 15, kq = lane >> 4;
    const int h = wid;

    // Preload Q fragments (already scaled by 0.125*log2e in the Q GEMM)
    short8 aq[2][2];   // [mt][kc]
#pragma unroll
    for (int mt = 0; mt < 2; ++mt)
#pragma unroll
        for (int kc = 0; kc < 2; ++kc)
            aq[mt][kc] = *(const short8*)&qb[
                (size_t)(b * 2048 + q0 + mt * 16 + ln) * 1024 +
                h * 64 + kc * 32 + kq * 8];

    float4v cacc[2][4] = {};   // [mt][nt] ctx accumulators (32q x 64d)

#pragma unroll 1
    for (int t = 0; t < 32; ++t) {
        const int kt = (kh << 10) + (t << 5);
        const int cur = t & 1;
        float* E = Ef[cur];

        // ---- S^T = K @ Q^T for this head (C: col=q=ln, row=k=kq*4+r)
        short8 bk[2][2];   // [kc][nt]
#pragma unroll
        for (int kc = 0; kc < 2; ++kc)
#pragma unroll
            for (int nt = 0; nt < 2; ++nt)
                bk[kc][nt] = *(const short8*)&kb[
                    (size_t)(b * 2048 + kt + nt * 16 + ln) * 1024 +
                    h * 64 + kc * 32 + kq * 8];

        float4v sacc[2][2] = {};   // [mt][nt]
#pragma unroll
        for (int kc = 0; kc < 2; ++kc)
#pragma unroll
            for (int mt = 0; mt < 2; ++mt)
#pragma unroll
                for (int nt = 0; nt < 2; ++nt)
                    sacc[mt][nt] = __builtin_amdgcn_mfma_f32_16x16x32_bf16(
                        bk[kc][nt], aq[mt][kc], sacc[mt][nt], 0, 0, 0);

        // ---- E = exp2(S) fp32, one b128 store per (mt,nt)
#pragma unroll
        for (int mt = 0; mt < 2; ++mt)
#pragma unroll
            for (int nt = 0; nt < 2; ++nt) {
                float4v e;
#pragma unroll
                for (int r = 0; r < 4; ++r)
                    e[r] = exp2f(fminf(sacc[mt][nt][r], 115.0f));
                *(float4v*)&E[(h * 32 + mt * 16 + ln) * 36 + nt * 16 + kq * 4] = e;
            }

        // ---- hoisted V gather (consumed after BAR-B; hides global latency)
        short8 bv[4];
#pragma unroll
        for (int nt = 0; nt < 4; ++nt)
            bv[nt] = *(const short8*)&vt[
                (size_t)(b * 1024 + h * 64 + nt * 16 + ln) * 2048 + kt + kq * 8];

        __syncthreads();   // BAR-A: E[cur] complete

        // ---- Dinv = 1 / sum_h E  (1024 threads, one (q,k) pair each)
        {
            const int q = tid >> 5, kk = tid & 31;
            const float* ec = &E[q * 36 + kk];
            float d0 = 0.f, d1 = 0.f, d2 = 0.f, d3 = 0.f;
#pragma unroll
            for (int hh = 0; hh < 4; ++hh) {
                d0 += ec[(hh * 4 + 0) * (32 * 36)];
                d1 += ec[(hh * 4 + 1) * (32 * 36)];
                d2 += ec[(hh * 4 + 2) * (32 * 36)];
                d3 += ec[(hh * 4 + 3) * (32 * 36)];
            }
            Di[q * 36 + kk] = __builtin_amdgcn_rcpf((d0 + d1) + (d2 + d3));
        }
        __syncthreads();   // BAR-B: Di complete

        // ---- A-frag = (E * Dinv) packed bf16 via cvt_pk; ctx += A @ V
        short8 ap[2];
#pragma unroll
        for (int mt = 0; mt < 2; ++mt) {
            const float* ep = &E[(h * 32 + mt * 16 + ln) * 36 + kq * 8];
            const float* dp = &Di[(mt * 16 + ln) * 36 + kq * 8];
            float4v e0 = *(const float4v*)&ep[0];
            float4v e1 = *(const float4v*)&ep[4];
            float4v g0 = *(const float4v*)&dp[0];
            float4v g1 = *(const float4v*)&dp[4];
            u32 pk[4] __attribute__((aligned(16)));
            pk[0] = cvtpk(e0[0] * g0[0], e0[1] * g0[1]);
            pk[1] = cvtpk(e0[2] * g0[2], e0[3] * g0[3]);
            pk[2] = cvtpk(e1[0] * g1[0], e1[1] * g1[1]);
            pk[3] = cvtpk(e1[2] * g1[2], e1[3] * g1[3]);
            ap[mt] = *(short8*)pk;
        }
#pragma unroll
        for (int nt = 0; nt < 4; ++nt)
#pragma unroll
            for (int mt = 0; mt < 2; ++mt)
                cacc[mt][nt] = __builtin_amdgcn_mfma_f32_16x16x32_bf16(
                    ap[mt], bv[nt], cacc[mt][nt], 0, 0, 0);
    }

    // Epilogue: ctx[b*2048+q][h*64+d] += partial, via packed bf16 atomics.
    // A thread's 4 r-values are ROWS; col pairs live in adjacent LANES ->
    // ds_swizzle xor-1 pairs them, even lanes issue the atomic.
#pragma unroll
    for (int mt = 0; mt < 2; ++mt)
#pragma unroll
        for (int nt = 0; nt < 4; ++nt)
#pragma unroll
            for (int r = 0; r < 4; ++r) {
                union { float f; int i; } v; v.f = cacc[mt][nt][r];
                int pv = __builtin_amdgcn_ds_swizzle(v.i, 0x041F); // lane^1
                if (!(lane & 1)) {
                    union { int i; float f; } pw; pw.i = pv;
                    u32 d = cvtpk(v.f, pw.f);
                    int row = b * 2048 + q0 + mt * 16 + kq * 4 + r;
                    int col = h * 64 + nt * 16 + ln;   // ln even
                    u16* p = &ctx[(size_t)row * 1024 + col];
                    asm volatile("global_atomic_pk_add_bf16 %0, %1, off"
                                 :: "v"(p), "v"(d) : "memory");
                }
            }
}

// ---------------------------------------------------------------------------
extern "C" void kernel_launch(void* const* d_in, const int* in_sizes, int n_in,
                              void* d_out, int out_size, void* d_ws, size_t ws_size,
                              hipStream_t stream) {
    const float* x   = (const float*)d_in[0];   // [8192][1024] fp32
    const float* w_q = (const float*)d_in[1];   // [1024][1024] fp32 (K x N)
    const float* w_k = (const float*)d_in[2];
    const float* w_v = (const float*)d_in[3];
    const float* w_o = (const float*)d_in[4];

    char* ws = (char*)d_ws;
    const size_t SZ_W   = (size_t)1024 * 1024 * 2;   // 2 MiB
    const size_t SZ_TOK = (size_t)8192 * 1024 * 2;   // 16 MiB
    // ws layout (40 MiB): x_bf | wtq wtk wtv wto | q_buf
    // x_bf is DEAD after the QKV projections -> reused as the bf16 ctx
    // accumulation buffer (zeroed before attn).
    u16* x_bf  = (u16*)(ws);
    u16* wtq   = (u16*)(ws + SZ_TOK);
    u16* wtk   = (u16*)(ws + SZ_TOK + SZ_W);
    u16* wtv   = (u16*)(ws + SZ_TOK + 2 * SZ_W);
    u16* wto   = (u16*)(ws + SZ_TOK + 3 * SZ_W);
    u16* q_buf = (u16*)(ws + SZ_TOK + 4 * SZ_W);
    u16* ctx   = x_bf;                               // aliased (x_bf dead)
    // k_buf / vt_buf live in d_out (32 MiB fp32) -- dead before final GEMM writes it
    u16* k_buf  = (u16*)d_out;
    u16* vt_buf = (u16*)d_out + (size_t)8192 * 1024;

    // 0. convert x to bf16
    convert_x<<<4096, 256, 0, stream>>>(x, x_bf);

    // 1. transpose+convert weights to Bt (N x K) bf16 layout
    transpose_w<<<dim3(32, 32, 4), dim3(32, 8), 0, stream>>>(
        w_q, w_k, w_v, w_o, wtq, wtk, wtv, wto);

    // 2. QKV projections (Q pre-scaled by 0.125*log2e for exp2-domain scores;
    //    V written directly in transposed [b*1024+f][2048] layout)
    gemm_bt<<<dim3(8, 64), 256, 0, stream>>>(x_bf, wtq, q_buf, 8192, 1024, 1024, 0, 0.18033688f);
    gemm_bt<<<dim3(8, 64), 256, 0, stream>>>(x_bf, wtk, k_buf, 8192, 1024, 1024, 0, 1.0f);
    gemm_bt<<<dim3(8, 64), 256, 0, stream>>>(x_bf, wtv, vt_buf, 8192, 1024, 1024, 1, 1.0f);

    // 2b. zero the ctx accumulator (x_bf is dead now)
    zero_buf<<<4096, 256, 0, stream>>>((uint4v*)ctx);

    // 3. fused attention, k-half split, XCD-pinned (ctx += via bf16 atomics)
    attn_kernel<<<dim3(512), 1024, 0, stream>>>(q_buf, k_buf, vt_buf, ctx);

    // 4. output projection -> fp32 d_out (overwrites k_buf/vt_buf scratch)
    gemm_bt<<<dim3(8, 64), 256, 0, stream>>>(ctx, wto, d_out, 8192, 1024, 1024, 2, 1.0f);
}

// Round 6
// 535.847 us; speedup vs baseline: 1.3462x; 1.0209x over previous
//
#include <hip/hip_runtime.h>
#include <hip/hip_bf16.h>

typedef unsigned short u16;
typedef unsigned int u32;
typedef __attribute__((ext_vector_type(8))) short short8;   // bf16x8 MFMA frag (4 VGPR)
typedef __attribute__((ext_vector_type(4))) float float4v;  // fp32x4 acc
typedef __attribute__((ext_vector_type(4))) unsigned int uint4v; // 16B vector
typedef __attribute__((ext_vector_type(2))) unsigned int uint2v; // 8B vector

__device__ __forceinline__ u16 f2bf(float f) {
    union { float f; unsigned int u; } v; v.f = f;
    unsigned int r = v.u + 0x7fffu + ((v.u >> 16) & 1u);  // RNE
    return (u16)(r >> 16);
}

// packed fp32x2 -> bf16x2 (no builtin on gfx950; T12 recipe)
__device__ __forceinline__ u32 cvtpk(float lo, float hi) {
    u32 r;
    asm("v_cvt_pk_bf16_f32 %0, %1, %2" : "=v"(r) : "v"(lo), "v"(hi));
    return r;
}
// bf16 pair unpack: element 0 is low u16, element 1 is high u16
__device__ __forceinline__ float bflo(u32 u) {
    union { u32 u; float f; } v; v.u = u << 16; return v.f;
}
__device__ __forceinline__ float bfhi(u32 u) {
    union { u32 u; float f; } v; v.u = u & 0xffff0000u; return v.f;
}

// async 16B global -> LDS (lane i lands at ldsbase + i*16)
__device__ __forceinline__ void gld_lds16(const u16* g, u16* l) {
    __builtin_amdgcn_global_load_lds(
        (const __attribute__((address_space(1))) u32*)g,
        (__attribute__((address_space(3))) u32*)l, 16, 0, 0);
}

// ---------------------------------------------------------------------------
// x: fp32 [8192*1024] -> bf16. 8 elements/thread.
// ---------------------------------------------------------------------------
__global__ __launch_bounds__(256) void convert_x(
    const float* __restrict__ x, u16* __restrict__ xb) {
    int i = (blockIdx.x * 256 + threadIdx.x) * 8;
    float4v a = *(const float4v*)&x[i];
    float4v b = *(const float4v*)&x[i + 4];
    u16 tmp[8] __attribute__((aligned(16)));
#pragma unroll
    for (int j = 0; j < 4; ++j) { tmp[j] = f2bf(a[j]); tmp[4 + j] = f2bf(b[j]); }
    *(uint4v*)&xb[i] = *(uint4v*)tmp;
}

// ---------------------------------------------------------------------------
// Weight transpose+convert: W fp32 [1024][1024] (K x N) -> Wt bf16 (N x K).
// ---------------------------------------------------------------------------
__global__ __launch_bounds__(256) void transpose_w(
    const float* __restrict__ w0, const float* __restrict__ w1,
    const float* __restrict__ w2, const float* __restrict__ w3,
    u16* __restrict__ o0, u16* __restrict__ o1,
    u16* __restrict__ o2, u16* __restrict__ o3) {
    __shared__ u16 t[32][33];
    int z = blockIdx.z;
    const float* w = (z == 0) ? w0 : (z == 1) ? w1 : (z == 2) ? w2 : w3;
    u16* o         = (z == 0) ? o0 : (z == 1) ? o1 : (z == 2) ? o2 : o3;
    int bx = blockIdx.x * 32;   // input col (n)
    int by = blockIdx.y * 32;   // input row (k)
    int x = threadIdx.x, y = threadIdx.y;   // block (32,8)
#pragma unroll
    for (int i = 0; i < 4; ++i)
        t[y + i * 8][x] = f2bf(w[(size_t)(by + y + i * 8) * 1024 + bx + x]);
    __syncthreads();
#pragma unroll
    for (int i = 0; i < 4; ++i)
        o[(size_t)(bx + y + i * 8) * 1024 + by + x] = t[x][y + i * 8];
}

// ---------------------------------------------------------------------------
// GEMM: C[M][N] = A[M][K] @ Bt[N][K]^T, bf16 in, fp32 accum.
// mode 0: bf16 out, scaled by oscale (folds softmax scale into Q proj)
// mode 1: bf16 out, transposed [b*1024+f][2048] (V)
// mode 2: fp32 out (final projection)
// ---------------------------------------------------------------------------
__global__ __launch_bounds__(256) void gemm_bt(
    const u16* __restrict__ A, const u16* __restrict__ Bt,
    void* __restrict__ Cout, int M, int N, int K, int mode, float oscale) {
    __shared__ __attribute__((aligned(16))) u16 As[128 * 32];
    __shared__ __attribute__((aligned(16))) u16 Bs[128 * 32];
    const int tid = threadIdx.x;
    const int m0 = blockIdx.y * 128;
    const int n0 = blockIdx.x * 128;
    const int wid = tid >> 6;
    const int lane = tid & 63;
    const int ln = lane & 15, kq = lane >> 4;
    const int wm = (wid >> 1) * 64, wn = (wid & 1) * 64;

    float4v acc[4][4] = {};
    for (int k0 = 0; k0 < K; k0 += 32) {
#pragma unroll
        for (int i = 0; i < 2; ++i) {
            int chunk = tid + i * 256;          // 16B chunk id, 0..511
            int row = chunk >> 2, cg = chunk & 3;
            u16* lA = &As[(size_t)(i * 256 + wid * 64) * 8];
            u16* lB = &Bs[(size_t)(i * 256 + wid * 64) * 8];
            gld_lds16(&A[(size_t)(m0 + row) * K + k0 + cg * 8], lA);
            gld_lds16(&Bt[(size_t)(n0 + row) * K + k0 + cg * 8], lB);
        }
        __syncthreads();
        short8 af[4], bfr[4];
#pragma unroll
        for (int mt = 0; mt < 4; ++mt)
            af[mt] = *(const short8*)&As[(wm + mt * 16 + ln) * 32 + kq * 8];
#pragma unroll
        for (int nt = 0; nt < 4; ++nt)
            bfr[nt] = *(const short8*)&Bs[(wn + nt * 16 + ln) * 32 + kq * 8];
#pragma unroll
        for (int mt = 0; mt < 4; ++mt)
#pragma unroll
            for (int nt = 0; nt < 4; ++nt)
                acc[mt][nt] = __builtin_amdgcn_mfma_f32_16x16x32_bf16(
                    af[mt], bfr[nt], acc[mt][nt], 0, 0, 0);
        __syncthreads();
    }
    if (mode == 0) {
        u16* C = (u16*)Cout;
#pragma unroll
        for (int mt = 0; mt < 4; ++mt)
#pragma unroll
            for (int nt = 0; nt < 4; ++nt)
#pragma unroll
                for (int r = 0; r < 4; ++r) {
                    int row = m0 + wm + mt * 16 + kq * 4 + r;
                    int col = n0 + wn + nt * 16 + ln;
                    C[(size_t)row * N + col] = f2bf(acc[mt][nt][r] * oscale);
                }
    } else if (mode == 1) {
        u16* C = (u16*)Cout;
#pragma unroll
        for (int mt = 0; mt < 4; ++mt)
#pragma unroll
            for (int nt = 0; nt < 4; ++nt)
#pragma unroll
                for (int r = 0; r < 4; ++r) {
                    int t = m0 + wm + mt * 16 + kq * 4 + r;
                    int col = n0 + wn + nt * 16 + ln;
                    int b = t >> 11, n = t & 2047;
                    C[((size_t)(b * 1024 + col)) * 2048 + n] = f2bf(acc[mt][nt][r]);
                }
    } else {
        float* C = (float*)Cout;
#pragma unroll
        for (int mt = 0; mt < 4; ++mt)
#pragma unroll
            for (int nt = 0; nt < 4; ++nt)
#pragma unroll
                for (int r = 0; r < 4; ++r) {
                    int row = m0 + wm + mt * 16 + kq * 4 + r;
                    int col = n0 + wn + nt * 16 + ln;
                    C[(size_t)row * N + col] = acc[mt][nt][r];
                }
    }
}

// ---------------------------------------------------------------------------
// Fused attention, head-axis softmax.  R11 = R8 pipeline, un-starved.
// R8's single-barrier software pipeline was correct but poisoned by
// __launch_bounds__(1024,4) -> 64-VGPR clamp -> remat/spill churn (counter
// evidence: WRITE_SIZE +5MB, MfmaUtil DOWN).  A 1024-thread block already
// forces 4 waves/SIMD, so plain __launch_bounds__(1024) grants the full
// 128-VGPR budget at identical occupancy.
// Window i: K-load(i) | V-load(i-1)->bvB | ap+PV(i-2) | S+Estore(i) |
//           Dsum(i-1) | ONE barrier.  All pipes busy every window.
//  * E bf16, 3 rotating buffers (write i / Dsum i-1 / ap-read i-2),
//    stride 36 u16; buffer selection by pointer rotation (no %3 VALU).
//  * Di fp32, 2 ping-pong buffers.
//  * Dsum: 4 waves x b64 reads (other 12 waves proceed to S/E phases).
// LDS = 3*36864 (E) + 2*4608 (Di) = 119808 B -> 1 block/CU (as before).
// Live regs ~110 (aq16+bk16+bvA16+bvB16+sacc16+temps) + cacc in AGPRs.
// qb/cb alias -- block reads its own 32 Q rows before writing same rows.
// ---------------------------------------------------------------------------
__global__ __launch_bounds__(1024) void attn_kernel(
    const u16* qb, const u16* __restrict__ kb,
    const u16* __restrict__ vt, u16* cb) {
    // E rows = h*32+q (512 rows), cols k 0..31 bf16, stride 36 u16 (72 B)
    __shared__ __attribute__((aligned(16))) u16   Ebuf[3][512 * 36]; // 110592 B
    __shared__ __attribute__((aligned(16))) float Dibuf[2][32 * 36]; //   9216 B

    const int b = blockIdx.y;
    const int q0 = blockIdx.x * 32;
    const int tid = threadIdx.x;
    const int wid = tid >> 6, lane = tid & 63;   // wid 0..15 = head
    const int ln = lane & 15, kq = lane >> 4;
    const int h = wid;

    // Preload Q fragments (already scaled by 0.125*log2e in the Q GEMM)
    short8 aq[2][2];   // [mt][kc]
#pragma unroll
    for (int mt = 0; mt < 2; ++mt)
#pragma unroll
        for (int kc = 0; kc < 2; ++kc)
            aq[mt][kc] = *(const short8*)&qb[
                (size_t)(b * 2048 + q0 + mt * 16 + ln) * 1024 +
                h * 64 + kc * 32 + kq * 8];

    float4v cacc[2][4] = {};   // [mt][nt] ctx accumulators (32q x 64d)
    short8 bvA[4], bvB[4];     // V frags: bvA = tile i-2 (consume), bvB = i-1

    // rotating E buffer pointers: window i writes Ew, Dsum reads Ed(i-1),
    // ap reads Ea(i-2).  rotation: (Ew,Ed,Ea) <- (Ea,Ew,Ed).
    u16* Ew = Ebuf[0];
    u16* Ed = Ebuf[2];   // garbage until i>=1 guard allows its use
    u16* Ea = Ebuf[1];
    float* Dw = Dibuf[0];   // window i writes Di(i-1)
    float* Da = Dibuf[1];   // ap reads Di(i-2)

    const int NT = 64;         // 2048 / 32
#pragma unroll 1
    for (int i = 0; i < NT + 2; ++i) {
        // ---- A: K loads for tile i (consumed in phase C, after PV block)
        short8 bk[2][2];   // [kc][nt]
        if (i < NT) {
            const int kt = i * 32;
#pragma unroll
            for (int kc = 0; kc < 2; ++kc)
#pragma unroll
                for (int nt = 0; nt < 2; ++nt)
                    bk[kc][nt] = *(const short8*)&kb[
                        (size_t)(b * 2048 + kt + nt * 16 + ln) * 1024 +
                        h * 64 + kc * 32 + kq * 8];
        }
        // ---- V loads for tile i-1 into bvB (consumed NEXT window)
        if (i >= 1 && i <= NT) {
            const int kt = (i - 1) * 32;
#pragma unroll
            for (int nt = 0; nt < 4; ++nt)
                bvB[nt] = *(const short8*)&vt[
                    (size_t)(b * 1024 + h * 64 + nt * 16 + ln) * 2048 + kt + kq * 8];
        }
        // ---- B: ap-build + PV for tile i-2 (E/Di crossed >=1 barrier)
        if (i >= 2) {
            short8 ap[2];
#pragma unroll
            for (int mt = 0; mt < 2; ++mt) {
                const u16* ep = &Ea[(h * 32 + mt * 16 + ln) * 36 + kq * 8];
                uint2v ea = *(const uint2v*)&ep[0];   // k = 8kq+0..3
                uint2v eb = *(const uint2v*)&ep[4];   // k = 8kq+4..7
                const float* dp = &Da[(mt * 16 + ln) * 36 + kq * 8];
                float4v g0 = *(const float4v*)&dp[0];
                float4v g1 = *(const float4v*)&dp[4];
                u32 pk[4] __attribute__((aligned(16)));
                pk[0] = cvtpk(bflo(ea[0]) * g0[0], bfhi(ea[0]) * g0[1]);
                pk[1] = cvtpk(bflo(ea[1]) * g0[2], bfhi(ea[1]) * g0[3]);
                pk[2] = cvtpk(bflo(eb[0]) * g1[0], bfhi(eb[0]) * g1[1]);
                pk[3] = cvtpk(bflo(eb[1]) * g1[2], bfhi(eb[1]) * g1[3]);
                ap[mt] = *(short8*)pk;
            }
#pragma unroll
            for (int nt = 0; nt < 4; ++nt)
#pragma unroll
                for (int mt = 0; mt < 2; ++mt)
                    cacc[mt][nt] = __builtin_amdgcn_mfma_f32_16x16x32_bf16(
                        ap[mt], bvA[nt], cacc[mt][nt], 0, 0, 0);
        }
        // ---- C: S^T = K @ Q^T, exp2, bf16 E-store for tile i
        if (i < NT) {
            float4v sacc[2][2] = {};   // [mt][nt]; C: col=q=ln, row=k=kq*4+r
#pragma unroll
            for (int kc = 0; kc < 2; ++kc)
#pragma unroll
                for (int mt = 0; mt < 2; ++mt)
#pragma unroll
                    for (int nt = 0; nt < 2; ++nt)
                        sacc[mt][nt] = __builtin_amdgcn_mfma_f32_16x16x32_bf16(
                            bk[kc][nt], aq[mt][kc], sacc[mt][nt], 0, 0, 0);
#pragma unroll
            for (int mt = 0; mt < 2; ++mt)
#pragma unroll
                for (int nt = 0; nt < 2; ++nt) {
                    float e0 = exp2f(fminf(sacc[mt][nt][0], 115.0f));
                    float e1 = exp2f(fminf(sacc[mt][nt][1], 115.0f));
                    float e2 = exp2f(fminf(sacc[mt][nt][2], 115.0f));
                    float e3 = exp2f(fminf(sacc[mt][nt][3], 115.0f));
                    uint2v w; w[0] = cvtpk(e0, e1); w[1] = cvtpk(e2, e3);
                    *(uint2v*)&Ew[(h * 32 + mt * 16 + ln) * 36 + nt * 16 + kq * 4] = w;
                }
        }
        // ---- D: Dsum for tile i-1 (waves 0..3; other waves run phase C)
        if (i >= 1 && i <= NT && tid < 256) {
            const int q = tid >> 3, k4 = tid & 7;   // k = k4*4 .. +3
            float d0 = 0.f, d1 = 0.f, d2 = 0.f, d3 = 0.f;
#pragma unroll
            for (int hh = 0; hh < 16; ++hh) {
                uint2v e = *(const uint2v*)&Ed[(hh * 32 + q) * 36 + k4 * 4];
                d0 += bflo(e[0]); d1 += bfhi(e[0]);
                d2 += bflo(e[1]); d3 += bfhi(e[1]);
            }
            float4v dv;
            dv[0] = __builtin_amdgcn_rcpf(d0);
            dv[1] = __builtin_amdgcn_rcpf(d1);
            dv[2] = __builtin_amdgcn_rcpf(d2);
            dv[3] = __builtin_amdgcn_rcpf(d3);
            *(float4v*)&Dw[q * 36 + k4 * 4] = dv;
        }
        __syncthreads();   // the single barrier per window
        // rotate buffers and V ping-pong regs
        { u16* t0 = Ew; Ew = Ea; Ea = Ed; Ed = t0; }
        { float* t1 = Dw; Dw = Da; Da = t1; }
#pragma unroll
        for (int nt = 0; nt < 4; ++nt) bvA[nt] = bvB[nt];
    }

    // Epilogue: ctx[b*2048+q][h*64+d], bf16  (cb aliases qb -- same rows only)
#pragma unroll
    for (int mt = 0; mt < 2; ++mt)
#pragma unroll
        for (int nt = 0; nt < 4; ++nt)
#pragma unroll
            for (int r = 0; r < 4; ++r) {
                int row = b * 2048 + q0 + mt * 16 + kq * 4 + r;
                int col = h * 64 + nt * 16 + ln;
                cb[(size_t)row * 1024 + col] = f2bf(cacc[mt][nt][r]);
            }
}

// ---------------------------------------------------------------------------
extern "C" void kernel_launch(void* const* d_in, const int* in_sizes, int n_in,
                              void* d_out, int out_size, void* d_ws, size_t ws_size,
                              hipStream_t stream) {
    const float* x   = (const float*)d_in[0];   // [8192][1024] fp32
    const float* w_q = (const float*)d_in[1];   // [1024][1024] fp32 (K x N)
    const float* w_k = (const float*)d_in[2];
    const float* w_v = (const float*)d_in[3];
    const float* w_o = (const float*)d_in[4];

    char* ws = (char*)d_ws;
    const size_t SZ_W   = (size_t)1024 * 1024 * 2;   // 2 MiB
    const size_t SZ_TOK = (size_t)8192 * 1024 * 2;   // 16 MiB
    // ws layout (40 MiB): x_bf | wtq wtk wtv wto | q_buf(=ctx)
    u16* x_bf  = (u16*)(ws);
    u16* wtq   = (u16*)(ws + SZ_TOK);
    u16* wtk   = (u16*)(ws + SZ_TOK + SZ_W);
    u16* wtv   = (u16*)(ws + SZ_TOK + 2 * SZ_W);
    u16* wto   = (u16*)(ws + SZ_TOK + 3 * SZ_W);
    u16* q_buf = (u16*)(ws + SZ_TOK + 4 * SZ_W);     // also ctx (aliased)
    // k_buf / vt_buf live in d_out (32 MiB fp32) -- dead before final GEMM writes it
    u16* k_buf  = (u16*)d_out;
    u16* vt_buf = (u16*)d_out + (size_t)8192 * 1024;

    // 0. convert x to bf16
    convert_x<<<4096, 256, 0, stream>>>(x, x_bf);

    // 1. transpose+convert weights to Bt (N x K) bf16 layout
    transpose_w<<<dim3(32, 32, 4), dim3(32, 8), 0, stream>>>(
        w_q, w_k, w_v, w_o, wtq, wtk, wtv, wto);

    // 2. QKV projections (Q pre-scaled by 0.125*log2e for exp2-domain scores;
    //    V written directly in transposed [b*1024+f][2048] layout)
    gemm_bt<<<dim3(8, 64), 256, 0, stream>>>(x_bf, wtq, q_buf, 8192, 1024, 1024, 0, 0.18033688f);
    gemm_bt<<<dim3(8, 64), 256, 0, stream>>>(x_bf, wtk, k_buf, 8192, 1024, 1024, 0, 1.0f);
    gemm_bt<<<dim3(8, 64), 256, 0, stream>>>(x_bf, wtv, vt_buf, 8192, 1024, 1024, 1, 1.0f);

    // 3. fused attention with head-axis softmax (ctx written into q_buf)
    attn_kernel<<<dim3(64, 4), 1024, 0, stream>>>(q_buf, k_buf, vt_buf, q_buf);

    // 4. output projection -> fp32 d_out (overwrites k_buf/vt_buf scratch)
    gemm_bt<<<dim3(8, 64), 256, 0, stream>>>(q_buf, wto, d_out, 8192, 1024, 1024, 2, 1.0f);
}

// Round 7
// 482.531 us; speedup vs baseline: 1.4949x; 1.1105x over previous
//
#include <hip/hip_runtime.h>
#include <hip/hip_bf16.h>

typedef unsigned short u16;
typedef unsigned int u32;
typedef __attribute__((ext_vector_type(8))) short short8;   // bf16x8 MFMA frag (4 VGPR)
typedef __attribute__((ext_vector_type(4))) float float4v;  // fp32x4 acc
typedef __attribute__((ext_vector_type(4))) unsigned int uint4v; // 16B vector
typedef __attribute__((ext_vector_type(2))) unsigned int uint2v; // 8B vector
typedef __attribute__((ext_vector_type(2))) float float2v;  // 8B float pair

__device__ __forceinline__ u16 f2bf(float f) {
    union { float f; unsigned int u; } v; v.f = f;
    unsigned int r = v.u + 0x7fffu + ((v.u >> 16) & 1u);  // RNE
    return (u16)(r >> 16);
}

// packed fp32x2 -> bf16x2 (no builtin on gfx950; T12 recipe)
__device__ __forceinline__ u32 cvtpk(float lo, float hi) {
    u32 r;
    asm("v_cvt_pk_bf16_f32 %0, %1, %2" : "=v"(r) : "v"(lo), "v"(hi));
    return r;
}
// bf16 pair unpack: element 0 is low u16, element 1 is high u16
__device__ __forceinline__ float bflo(u32 u) {
    union { u32 u; float f; } v; v.u = u << 16; return v.f;
}
__device__ __forceinline__ float bfhi(u32 u) {
    union { u32 u; float f; } v; v.u = u & 0xffff0000u; return v.f;
}

// async 16B global -> LDS (lane i lands at ldsbase + i*16)
__device__ __forceinline__ void gld_lds16(const u16* g, u16* l) {
    __builtin_amdgcn_global_load_lds(
        (const __attribute__((address_space(1))) u32*)g,
        (__attribute__((address_space(3))) u32*)l, 16, 0, 0);
}

// ---------------------------------------------------------------------------
// x: fp32 [8192*1024] -> bf16. 8 elements/thread.
// ---------------------------------------------------------------------------
__global__ __launch_bounds__(256) void convert_x(
    const float* __restrict__ x, u16* __restrict__ xb) {
    int i = (blockIdx.x * 256 + threadIdx.x) * 8;
    float4v a = *(const float4v*)&x[i];
    float4v b = *(const float4v*)&x[i + 4];
    u16 tmp[8] __attribute__((aligned(16)));
#pragma unroll
    for (int j = 0; j < 4; ++j) { tmp[j] = f2bf(a[j]); tmp[4 + j] = f2bf(b[j]); }
    *(uint4v*)&xb[i] = *(uint4v*)tmp;
}

// ---------------------------------------------------------------------------
// Weight transpose+convert: W fp32 [1024][1024] (K x N) -> Wt bf16 (N x K).
// ---------------------------------------------------------------------------
__global__ __launch_bounds__(256) void transpose_w(
    const float* __restrict__ w0, const float* __restrict__ w1,
    const float* __restrict__ w2, const float* __restrict__ w3,
    u16* __restrict__ o0, u16* __restrict__ o1,
    u16* __restrict__ o2, u16* __restrict__ o3) {
    __shared__ u16 t[32][33];
    int z = blockIdx.z;
    const float* w = (z == 0) ? w0 : (z == 1) ? w1 : (z == 2) ? w2 : w3;
    u16* o         = (z == 0) ? o0 : (z == 1) ? o1 : (z == 2) ? o2 : o3;
    int bx = blockIdx.x * 32;   // input col (n)
    int by = blockIdx.y * 32;   // input row (k)
    int x = threadIdx.x, y = threadIdx.y;   // block (32,8)
#pragma unroll
    for (int i = 0; i < 4; ++i)
        t[y + i * 8][x] = f2bf(w[(size_t)(by + y + i * 8) * 1024 + bx + x]);
    __syncthreads();
#pragma unroll
    for (int i = 0; i < 4; ++i)
        o[(size_t)(bx + y + i * 8) * 1024 + by + x] = t[x][y + i * 8];
}

// ---------------------------------------------------------------------------
// GEMM: C[M][N] = A[M][K] @ Bt[N][K]^T, bf16 in, fp32 accum.
// mode 0: bf16 out, scaled by oscale (folds softmax scale into Q proj)
// mode 1: bf16 out, transposed [b*1024+f][2048] (V)
// mode 2: fp32 out (final projection)
// ---------------------------------------------------------------------------
__global__ __launch_bounds__(256) void gemm_bt(
    const u16* __restrict__ A, const u16* __restrict__ Bt,
    void* __restrict__ Cout, int M, int N, int K, int mode, float oscale) {
    __shared__ __attribute__((aligned(16))) u16 As[128 * 32];
    __shared__ __attribute__((aligned(16))) u16 Bs[128 * 32];
    const int tid = threadIdx.x;
    const int m0 = blockIdx.y * 128;
    const int n0 = blockIdx.x * 128;
    const int wid = tid >> 6;
    const int lane = tid & 63;
    const int ln = lane & 15, kq = lane >> 4;
    const int wm = (wid >> 1) * 64, wn = (wid & 1) * 64;

    float4v acc[4][4] = {};
    for (int k0 = 0; k0 < K; k0 += 32) {
#pragma unroll
        for (int i = 0; i < 2; ++i) {
            int chunk = tid + i * 256;          // 16B chunk id, 0..511
            int row = chunk >> 2, cg = chunk & 3;
            u16* lA = &As[(size_t)(i * 256 + wid * 64) * 8];
            u16* lB = &Bs[(size_t)(i * 256 + wid * 64) * 8];
            gld_lds16(&A[(size_t)(m0 + row) * K + k0 + cg * 8], lA);
            gld_lds16(&Bt[(size_t)(n0 + row) * K + k0 + cg * 8], lB);
        }
        __syncthreads();
        short8 af[4], bfr[4];
#pragma unroll
        for (int mt = 0; mt < 4; ++mt)
            af[mt] = *(const short8*)&As[(wm + mt * 16 + ln) * 32 + kq * 8];
#pragma unroll
        for (int nt = 0; nt < 4; ++nt)
            bfr[nt] = *(const short8*)&Bs[(wn + nt * 16 + ln) * 32 + kq * 8];
#pragma unroll
        for (int mt = 0; mt < 4; ++mt)
#pragma unroll
            for (int nt = 0; nt < 4; ++nt)
                acc[mt][nt] = __builtin_amdgcn_mfma_f32_16x16x32_bf16(
                    af[mt], bfr[nt], acc[mt][nt], 0, 0, 0);
        __syncthreads();
    }
    if (mode == 0) {
        u16* C = (u16*)Cout;
#pragma unroll
        for (int mt = 0; mt < 4; ++mt)
#pragma unroll
            for (int nt = 0; nt < 4; ++nt)
#pragma unroll
                for (int r = 0; r < 4; ++r) {
                    int row = m0 + wm + mt * 16 + kq * 4 + r;
                    int col = n0 + wn + nt * 16 + ln;
                    C[(size_t)row * N + col] = f2bf(acc[mt][nt][r] * oscale);
                }
    } else if (mode == 1) {
        u16* C = (u16*)Cout;
#pragma unroll
        for (int mt = 0; mt < 4; ++mt)
#pragma unroll
            for (int nt = 0; nt < 4; ++nt)
#pragma unroll
                for (int r = 0; r < 4; ++r) {
                    int t = m0 + wm + mt * 16 + kq * 4 + r;
                    int col = n0 + wn + nt * 16 + ln;
                    int b = t >> 11, n = t & 2047;
                    C[((size_t)(b * 1024 + col)) * 2048 + n] = f2bf(acc[mt][nt][r]);
                }
    } else {
        float* C = (float*)Cout;
#pragma unroll
        for (int mt = 0; mt < 4; ++mt)
#pragma unroll
            for (int nt = 0; nt < 4; ++nt)
#pragma unroll
                for (int r = 0; r < 4; ++r) {
                    int row = m0 + wm + mt * 16 + kq * 4 + r;
                    int col = n0 + wn + nt * 16 + ln;
                    C[(size_t)row * N + col] = acc[mt][nt][r];
                }
    }
}

// ---------------------------------------------------------------------------
// Fused attention, head-axis softmax.  R12 = R7 structure, k-tile 32 -> 64.
// Counter evidence R7-R11: per-WINDOW fixed cost (2 barrier drains + global
// latency exposure + serial Dsum gap) ~ 6K cy dominates; VALU work ~3.7K;
// pipelining fails on the 64-VGPR wall (R6/R8/R11 all spill).  So: amortize
// the fixed cost over 2x work -- 32 windows of k64 instead of 64 of k32.
//  * S-phase runs k64 as TWO sequential 32-halves: live set stays R7-sized
//    (aq16 + bk16 + sacc16) -- no new register pressure in the hot phase.
//  * E bf16 (proven R8/R9, absmax unchanged), stride 72 u16 (144 B):
//    E-store/Dsum-read/ap-read all land exactly on LDS bank floors.
//  * Dsum 2x efficient: one u32 read = a bf16 PAIR; 16 reads -> 2 col sums
//    (thread (q=tid>>5, kk=tid&31) owns k=2kk,2kk+1).
//  * Di fp32 stride 68 (b128 ap-reads at bank floor).
// LDS = 2*73728 (E) + 8704 (Di) = 156160 B -> 1 block/CU.
// qb/cb alias -- block reads its own 32 Q rows before writing same rows.
// ---------------------------------------------------------------------------
__global__ __launch_bounds__(1024) void attn_kernel(
    const u16* qb, const u16* __restrict__ kb,
    const u16* __restrict__ vt, u16* cb) {
    // E rows = h*32+q (512), cols k 0..63 bf16, stride 72 u16 (144 B)
    __shared__ __attribute__((aligned(16))) u16   Ebuf[2][512 * 72]; // 147456 B
    __shared__ __attribute__((aligned(16))) float Di[32 * 68];       //   8704 B

    const int b = blockIdx.y;
    const int q0 = blockIdx.x * 32;
    const int tid = threadIdx.x;
    const int wid = tid >> 6, lane = tid & 63;   // wid 0..15 = head
    const int ln = lane & 15, kq = lane >> 4;
    const int h = wid;

    // Preload Q fragments (already scaled by 0.125*log2e in the Q GEMM)
    short8 aq[2][2];   // [mt][kc]
#pragma unroll
    for (int mt = 0; mt < 2; ++mt)
#pragma unroll
        for (int kc = 0; kc < 2; ++kc)
            aq[mt][kc] = *(const short8*)&qb[
                (size_t)(b * 2048 + q0 + mt * 16 + ln) * 1024 +
                h * 64 + kc * 32 + kq * 8];

    float4v cacc[2][4] = {};   // [mt][nt] ctx accumulators (32q x 64d)

#pragma unroll 1
    for (int t = 0; t < 32; ++t) {
        const int kt = t << 6;              // 64 keys per window
        u16* E = Ebuf[t & 1];

        // ---- S^T = K @ Q^T, exp2, bf16 E-store; two 32-key halves keep the
        //      live set at R7 size (aq16 + bk16 + sacc16).
#pragma unroll
        for (int c = 0; c < 2; ++c) {
            short8 bk[2][2];   // [kc][nt]
#pragma unroll
            for (int kc = 0; kc < 2; ++kc)
#pragma unroll
                for (int nt = 0; nt < 2; ++nt)
                    bk[kc][nt] = *(const short8*)&kb[
                        (size_t)(b * 2048 + kt + c * 32 + nt * 16 + ln) * 1024 +
                        h * 64 + kc * 32 + kq * 8];
            float4v sacc[2][2] = {};   // [mt][nt]; C: col=q=ln, row=k=kq*4+r
#pragma unroll
            for (int kc = 0; kc < 2; ++kc)
#pragma unroll
                for (int mt = 0; mt < 2; ++mt)
#pragma unroll
                    for (int nt = 0; nt < 2; ++nt)
                        sacc[mt][nt] = __builtin_amdgcn_mfma_f32_16x16x32_bf16(
                            bk[kc][nt], aq[mt][kc], sacc[mt][nt], 0, 0, 0);
#pragma unroll
            for (int mt = 0; mt < 2; ++mt)
#pragma unroll
                for (int nt = 0; nt < 2; ++nt) {
                    float e0 = exp2f(fminf(sacc[mt][nt][0], 115.0f));
                    float e1 = exp2f(fminf(sacc[mt][nt][1], 115.0f));
                    float e2 = exp2f(fminf(sacc[mt][nt][2], 115.0f));
                    float e3 = exp2f(fminf(sacc[mt][nt][3], 115.0f));
                    uint2v w; w[0] = cvtpk(e0, e1); w[1] = cvtpk(e2, e3);
                    *(uint2v*)&E[(h * 32 + mt * 16 + ln) * 72 +
                                 c * 32 + nt * 16 + kq * 4] = w;
                }
        }

        // ---- hoisted V gather (consumed after BAR-B; hides global latency)
        short8 bv[2][4];   // [c][nt]
#pragma unroll
        for (int c = 0; c < 2; ++c)
#pragma unroll
            for (int nt = 0; nt < 4; ++nt)
                bv[c][nt] = *(const short8*)&vt[
                    (size_t)(b * 1024 + h * 64 + nt * 16 + ln) * 2048 +
                    kt + c * 32 + kq * 8];

        __syncthreads();   // BAR-A: E[cur] complete

        // ---- Dinv = 1/sum_h E: thread (q=tid>>5, kk=tid&31) owns k=2kk,2kk+1
        {
            const int q = tid >> 5, kk = tid & 31;
            const u16* ec = &E[q * 72 + 2 * kk];
            float d0 = 0.f, d1 = 0.f, d2 = 0.f, d3 = 0.f;
#pragma unroll
            for (int hh = 0; hh < 8; ++hh) {
                u32 ea = *(const u32*)&ec[(2 * hh) * (32 * 72)];
                u32 eb = *(const u32*)&ec[(2 * hh + 1) * (32 * 72)];
                d0 += bflo(ea); d1 += bfhi(ea);
                d2 += bflo(eb); d3 += bfhi(eb);
            }
            float2v dv;
            dv[0] = __builtin_amdgcn_rcpf(d0 + d2);
            dv[1] = __builtin_amdgcn_rcpf(d1 + d3);
            *(float2v*)&Di[q * 68 + 2 * kk] = dv;
        }
        __syncthreads();   // BAR-B: Di complete

        // ---- A-frag = (E * Dinv) packed bf16 via cvt_pk; ctx += A @ V
#pragma unroll
        for (int mt = 0; mt < 2; ++mt) {
            short8 ap[2];
#pragma unroll
            for (int c = 0; c < 2; ++c) {
                const u16* ep = &E[(h * 32 + mt * 16 + ln) * 72 + c * 32 + kq * 8];
                uint2v ea = *(const uint2v*)&ep[0];   // k = +0..3
                uint2v eb = *(const uint2v*)&ep[4];   // k = +4..7
                const float* dp = &Di[(mt * 16 + ln) * 68 + c * 32 + kq * 8];
                float4v g0 = *(const float4v*)&dp[0];
                float4v g1 = *(const float4v*)&dp[4];
                u32 pk[4] __attribute__((aligned(16)));
                pk[0] = cvtpk(bflo(ea[0]) * g0[0], bfhi(ea[0]) * g0[1]);
                pk[1] = cvtpk(bflo(ea[1]) * g0[2], bfhi(ea[1]) * g0[3]);
                pk[2] = cvtpk(bflo(eb[0]) * g1[0], bfhi(eb[0]) * g1[1]);
                pk[3] = cvtpk(bflo(eb[1]) * g1[2], bfhi(eb[1]) * g1[3]);
                ap[c] = *(short8*)pk;
            }
#pragma unroll
            for (int nt = 0; nt < 4; ++nt) {
                cacc[mt][nt] = __builtin_amdgcn_mfma_f32_16x16x32_bf16(
                    ap[0], bv[0][nt], cacc[mt][nt], 0, 0, 0);
                cacc[mt][nt] = __builtin_amdgcn_mfma_f32_16x16x32_bf16(
                    ap[1], bv[1][nt], cacc[mt][nt], 0, 0, 0);
            }
        }
    }

    // Epilogue: ctx[b*2048+q][h*64+d], bf16  (cb aliases qb -- same rows only)
#pragma unroll
    for (int mt = 0; mt < 2; ++mt)
#pragma unroll
        for (int nt = 0; nt < 4; ++nt)
#pragma unroll
            for (int r = 0; r < 4; ++r) {
                int row = b * 2048 + q0 + mt * 16 + kq * 4 + r;
                int col = h * 64 + nt * 16 + ln;
                cb[(size_t)row * 1024 + col] = f2bf(cacc[mt][nt][r]);
            }
}

// ---------------------------------------------------------------------------
extern "C" void kernel_launch(void* const* d_in, const int* in_sizes, int n_in,
                              void* d_out, int out_size, void* d_ws, size_t ws_size,
                              hipStream_t stream) {
    const float* x   = (const float*)d_in[0];   // [8192][1024] fp32
    const float* w_q = (const float*)d_in[1];   // [1024][1024] fp32 (K x N)
    const float* w_k = (const float*)d_in[2];
    const float* w_v = (const float*)d_in[3];
    const float* w_o = (const float*)d_in[4];

    char* ws = (char*)d_ws;
    const size_t SZ_W   = (size_t)1024 * 1024 * 2;   // 2 MiB
    const size_t SZ_TOK = (size_t)8192 * 1024 * 2;   // 16 MiB
    // ws layout (40 MiB): x_bf | wtq wtk wtv wto | q_buf(=ctx)
    u16* x_bf  = (u16*)(ws);
    u16* wtq   = (u16*)(ws + SZ_TOK);
    u16* wtk   = (u16*)(ws + SZ_TOK + SZ_W);
    u16* wtv   = (u16*)(ws + SZ_TOK + 2 * SZ_W);
    u16* wto   = (u16*)(ws + SZ_TOK + 3 * SZ_W);
    u16* q_buf = (u16*)(ws + SZ_TOK + 4 * SZ_W);     // also ctx (aliased)
    // k_buf / vt_buf live in d_out (32 MiB fp32) -- dead before final GEMM writes it
    u16* k_buf  = (u16*)d_out;
    u16* vt_buf = (u16*)d_out + (size_t)8192 * 1024;

    // 0. convert x to bf16
    convert_x<<<4096, 256, 0, stream>>>(x, x_bf);

    // 1. transpose+convert weights to Bt (N x K) bf16 layout
    transpose_w<<<dim3(32, 32, 4), dim3(32, 8), 0, stream>>>(
        w_q, w_k, w_v, w_o, wtq, wtk, wtv, wto);

    // 2. QKV projections (Q pre-scaled by 0.125*log2e for exp2-domain scores;
    //    V written directly in transposed [b*1024+f][2048] layout)
    gemm_bt<<<dim3(8, 64), 256, 0, stream>>>(x_bf, wtq, q_buf, 8192, 1024, 1024, 0, 0.18033688f);
    gemm_bt<<<dim3(8, 64), 256, 0, stream>>>(x_bf, wtk, k_buf, 8192, 1024, 1024, 0, 1.0f);
    gemm_bt<<<dim3(8, 64), 256, 0, stream>>>(x_bf, wtv, vt_buf, 8192, 1024, 1024, 1, 1.0f);

    // 3. fused attention with head-axis softmax (ctx written into q_buf)
    attn_kernel<<<dim3(64, 4), 1024, 0, stream>>>(q_buf, k_buf, vt_buf, q_buf);

    // 4. output projection -> fp32 d_out (overwrites k_buf/vt_buf scratch)
    gemm_bt<<<dim3(8, 64), 256, 0, stream>>>(q_buf, wto, d_out, 8192, 1024, 1024, 2, 1.0f);
}